// Round 1
// baseline (621.968 us; speedup 1.0000x reference)
//
#include <hip/hip_runtime.h>

// Problem constants
#define NROWS 8192
#define DDIM  512
#define MEXP  2048
#define BDIM  4
#define KTOP  8

// d_out layout (floats): h_sparse [0,262144), idx [262144,327680), 7 scalars at 327680
#define OUT_HS_F4   0          // float4 index base for h_sparse
#define OUT_IDX     262144
#define OUT_SCAL    327680

// d_ws layout (bytes)
#define WS_VT_BYTES (2048u * 512u * 16u)   // 16 MiB: Vt[m][d] as float4 (b-dim)
#define WS_ESUM_OFF WS_VT_BYTES            // 2048 f32
#define WS_CNT_OFF  (WS_VT_BYTES + 8192u)  // 2048 u32
#define WS_SCAL_OFF (WS_VT_BYTES + 16384u) // [0]=captured_sum [1]=resid_sum [2]=recon_sum

// ---------------------------------------------------------------------------
// Kernel 1: per-row expert energy + top-8 selection + gathers + accumulators
// ---------------------------------------------------------------------------
__global__ __launch_bounds__(256) void energy_topk_kernel(
    const float* __restrict__ h_all, float* __restrict__ out,
    float* __restrict__ expert_sum, unsigned int* __restrict__ counts_g,
    float* __restrict__ scalars, int rows_per_block)
{
    __shared__ unsigned int s_counts[MEXP];
    __shared__ unsigned long long s_red[4];
    __shared__ int s_win_m[KTOP];

    const int t    = threadIdx.x;
    const int lane = t & 63;
    const int wid  = t >> 6;

    for (int j = t; j < MEXP; j += 256) s_counts[j] = 0u;
    __syncthreads();

    float esum[8];
#pragma unroll
    for (int j = 0; j < 8; ++j) esum[j] = 0.f;
    float cap_sum = 0.f;

    const int row0 = blockIdx.x * rows_per_block;
    for (int r = 0; r < rows_per_block; ++r) {
        const int n = row0 + r;
        const float4* __restrict__ hrow =
            (const float4*)(h_all + (size_t)n * (MEXP * BDIM));

        unsigned long long key[8];
#pragma unroll
        for (int j = 0; j < 8; ++j) {
            const int m = t + 256 * j;
            const float4 h = hrow[m];
            // bit-exact match to numpy f32 sequential sum of h*h (no FMA)
            float e = __fadd_rn(__fadd_rn(__fadd_rn(__fmul_rn(h.x, h.x),
                                                    __fmul_rn(h.y, h.y)),
                                          __fmul_rn(h.z, h.z)),
                                __fmul_rn(h.w, h.w));
            esum[j] += e;
            const unsigned int eb = __float_as_uint(e); // e >= 0 -> monotone bits
            key[j] = ((unsigned long long)eb << 32) |
                     (unsigned long long)(0xFFFFFFFFu - (unsigned int)m);
        }

        // 8 rounds of block-wide argmax (ties -> lower expert index)
        for (int kk = 0; kk < KTOP; ++kk) {
            unsigned long long v = 0ull;
#pragma unroll
            for (int j = 0; j < 8; ++j) v = (key[j] > v) ? key[j] : v;
#pragma unroll
            for (int off = 32; off > 0; off >>= 1) {
                unsigned long long o = __shfl_down(v, off, 64);
                v = (o > v) ? o : v;
            }
            if (lane == 0) s_red[wid] = v;
            __syncthreads();
            unsigned long long w = s_red[0];
#pragma unroll
            for (int i = 1; i < 4; ++i) {
                unsigned long long o = s_red[i];
                w = (o > w) ? o : w;
            }
            const int m = (int)(0xFFFFFFFFu - (unsigned int)(w & 0xFFFFFFFFull));
            const float e = __uint_as_float((unsigned int)(w >> 32));
            if (t == (m & 255)) {           // owner clears + counts
                key[m >> 8] = 0ull;
                s_counts[m] += 1u;
            }
            if (t == 0) {
                s_win_m[kk] = m;
                cap_sum += e;
                out[OUT_IDX + n * KTOP + kk] = (float)m;
            }
            __syncthreads();
        }

        // gather h_sparse[n,k,:] (L1/L2 hit: row just read)
        if (t < KTOP) {
            const int m = s_win_m[t];
            ((float4*)out)[(size_t)n * KTOP + t] = hrow[m];
        }
        __syncthreads();
    }

    // flush per-block accumulators
#pragma unroll
    for (int j = 0; j < 8; ++j) {
        const int m = t + 256 * j;
        atomicAdd(&expert_sum[m], esum[j]);
        const unsigned int c = s_counts[m];
        if (c) atomicAdd(&counts_g[m], c);
    }
    if (t == 0) atomicAdd(&scalars[0], cap_sum);
}

// ---------------------------------------------------------------------------
// Kernel 2: transpose V (D,M,B) -> Vt (M,D,B), float4 elements over b
// ---------------------------------------------------------------------------
__global__ __launch_bounds__(256) void transpose_v_kernel(
    const float4* __restrict__ V, float4* __restrict__ Vt)
{
    __shared__ float4 tile[32][33];
    const int bx = blockIdx.x;       // m tile: 0..63
    const int by = blockIdx.y;       // d tile: 0..15
    const int tx = threadIdx.x & 31;
    const int ty = threadIdx.x >> 5; // 0..7

#pragma unroll
    for (int i = 0; i < 4; ++i) {
        const int d = by * 32 + ty + i * 8;
        const int m = bx * 32 + tx;
        tile[ty + i * 8][tx] = V[(size_t)d * MEXP + m];
    }
    __syncthreads();
#pragma unroll
    for (int i = 0; i < 4; ++i) {
        const int m = bx * 32 + ty + i * 8;
        const int d = by * 32 + tx;
        Vt[(size_t)m * DDIM + d] = tile[tx][ty + i * 8];
    }
}

// ---------------------------------------------------------------------------
// Kernel 3: x_hat per row, residual & recon energy partial sums
// ---------------------------------------------------------------------------
__global__ __launch_bounds__(256) void recon_kernel(
    const float* __restrict__ x_flat, const float* __restrict__ out_ro,
    const float4* __restrict__ Vt, float* __restrict__ scalars)
{
    __shared__ float4 s_h[KTOP];
    __shared__ int    s_m[KTOP];
    __shared__ float  s_lr[4], s_lh[4];

    const int n    = blockIdx.x;
    const int t    = threadIdx.x;
    const int lane = t & 63;
    const int wid  = t >> 6;

    if (t < KTOP) {
        s_m[t] = (int)out_ro[OUT_IDX + n * KTOP + t];
        s_h[t] = ((const float4*)out_ro)[(size_t)n * KTOP + t];
    }
    __syncthreads();

    const int d0 = 2 * t, d1 = 2 * t + 1;
    float xh0 = 0.f, xh1 = 0.f;
#pragma unroll
    for (int k = 0; k < KTOP; ++k) {
        const int m = s_m[k];
        const float4 hv = s_h[k];
        const float4 v0 = Vt[(size_t)m * DDIM + d0];
        const float4 v1 = Vt[(size_t)m * DDIM + d1];
        xh0 += v0.x * hv.x + v0.y * hv.y + v0.z * hv.z + v0.w * hv.w;
        xh1 += v1.x * hv.x + v1.y * hv.y + v1.z * hv.z + v1.w * hv.w;
    }

    const float2 xv = ((const float2*)x_flat)[(size_t)n * 256 + t];
    const float r0 = xv.x - xh0, r1 = xv.y - xh1;
    float lr = r0 * r0 + r1 * r1;
    float lh = xh0 * xh0 + xh1 * xh1;

#pragma unroll
    for (int off = 32; off > 0; off >>= 1) {
        lr += __shfl_down(lr, off, 64);
        lh += __shfl_down(lh, off, 64);
    }
    if (lane == 0) { s_lr[wid] = lr; s_lh[wid] = lh; }
    __syncthreads();
    if (t == 0) {
        atomicAdd(&scalars[1], s_lr[0] + s_lr[1] + s_lr[2] + s_lr[3]);
        atomicAdd(&scalars[2], s_lh[0] + s_lh[1] + s_lh[2] + s_lh[3]);
    }
}

// ---------------------------------------------------------------------------
// Kernel 4: finalize scalars
// ---------------------------------------------------------------------------
__device__ __forceinline__ double block_reduce_d(double v, double* s4,
                                                 int lane, int wid)
{
#pragma unroll
    for (int off = 32; off > 0; off >>= 1) v += __shfl_down(v, off, 64);
    if (lane == 0) s4[wid] = v;
    __syncthreads();
    const double r = s4[0] + s4[1] + s4[2] + s4[3];
    __syncthreads();
    return r;
}

__global__ __launch_bounds__(256) void finalize_kernel(
    const float* __restrict__ expert_sum, const unsigned int* __restrict__ counts,
    const float* __restrict__ scalars, float* __restrict__ out)
{
    __shared__ double s4[4];
    const int t = threadIdx.x, lane = t & 63, wid = t >> 6;

    double avg[8];
    double tot = 0.0;
#pragma unroll
    for (int j = 0; j < 8; ++j) {
        avg[j] = (double)expert_sum[t + 256 * j] / (double)NROWS;
        tot += avg[j];
    }
    double denom = block_reduce_d(tot, s4, lane, wid);
    denom = (denom > 1e-8) ? denom : 1e-8;

    double entl = 0.0;
#pragma unroll
    for (int j = 0; j < 8; ++j) {
        double p = avg[j] / denom;
        p = (p > 1e-8) ? p : 1e-8;
        entl -= p * log(p);
    }
    const double entropy = block_reduce_d(entl, s4, lane, wid) / log(2048.0);

    double lowl = 0.0, deadl = 0.0;
    const float expected = (float)KTOP / (float)MEXP * (float)NROWS; // 32
#pragma unroll
    for (int j = 0; j < 8; ++j) {
        const float c = (float)counts[t + 256 * j];
        if (c <= 0.1f * expected)  lowl  += 1.0;
        if (c <= 0.01f * expected) deadl += 1.0;
    }
    const double low  = block_reduce_d(lowl, s4, lane, wid);
    const double dead = block_reduce_d(deadl, s4, lane, wid);

    if (t == 0) {
        const double captured = (double)scalars[0] / (double)NROWS;
        const double uncap    = (double)scalars[1] / (double)NROWS;
        const double recon    = (double)scalars[2] / (double)NROWS;
        out[OUT_SCAL + 0] = (float)captured;
        out[OUT_SCAL + 1] = (float)recon;
        out[OUT_SCAL + 2] = (float)uncap;
        out[OUT_SCAL + 3] = (float)entropy;
        out[OUT_SCAL + 4] = (float)(uncap + 0.01 * (1.0 - entropy));
        out[OUT_SCAL + 5] = (float)low;
        out[OUT_SCAL + 6] = (float)dead;
    }
}

// ---------------------------------------------------------------------------
extern "C" void kernel_launch(void* const* d_in, const int* in_sizes, int n_in,
                              void* d_out, int out_size, void* d_ws, size_t ws_size,
                              hipStream_t stream)
{
    const float* x = (const float*)d_in[0];
    const float* h = (const float*)d_in[1];
    const float* V = (const float*)d_in[2];
    float* out = (float*)d_out;
    char*  ws  = (char*)d_ws;

    float4*       Vt         = (float4*)ws;
    float*        expert_sum = (float*)(ws + WS_ESUM_OFF);
    unsigned int* counts     = (unsigned int*)(ws + WS_CNT_OFF);
    float*        scalars    = (float*)(ws + WS_SCAL_OFF);

    // zero accumulators (ws is poisoned 0xAA before every call)
    hipMemsetAsync(ws + WS_ESUM_OFF, 0, 16384 + 64, stream);

    transpose_v_kernel<<<dim3(64, 16), 256, 0, stream>>>((const float4*)V, Vt);
    energy_topk_kernel<<<1024, 256, 0, stream>>>(h, out, expert_sum, counts,
                                                 scalars, NROWS / 1024);
    recon_kernel<<<NROWS, 256, 0, stream>>>(x, out, Vt, scalars);
    finalize_kernel<<<1, 256, 0, stream>>>(expert_sum, counts, scalars, out);
}